// Round 1
// baseline (22.712 us; speedup 1.0000x reference)
//
#include <hip/hip_runtime.h>

#define N_ATT   2048
#define B_ROWS  32
#define SPLITS  8          // blocks per row; SPLITS*THREADS == N_ATT
#define THREADS 256
#define C_CLS   10
#define BETA    0.5f
#define EPS_ATT 1e-6f

// Kernel 1: per-(row,split) partial Gini sums.
// grid = B_ROWS*SPLITS blocks; block b handles row b/SPLITS, i-range
// [split*256, split*256+255]. Row staged in LDS as log(att+eps).
__global__ __launch_bounds__(THREADS)
void gini_partial(const float* __restrict__ att, float* __restrict__ ws) {
    __shared__ float xs[N_ATT];
    const int row   = blockIdx.x / SPLITS;
    const int split = blockIdx.x % SPLITS;
    const int t     = threadIdx.x;
    const float* a  = att + row * N_ATT;

    // stage row into LDS (coalesced global loads, log once per element)
#pragma unroll
    for (int k = 0; k < N_ATT / THREADS; ++k) {
        const int idx = t + k * THREADS;
        xs[idx] = logf(a[idx] + EPS_ATT);
    }
    __syncthreads();

    const float xi = xs[split * THREADS + t];

    // sum_j |xi - xs[j]| ; float4 LDS reads (same addr per iter -> broadcast)
    float s0 = 0.f, s1 = 0.f, s2 = 0.f, s3 = 0.f;
    const float4* xs4 = reinterpret_cast<const float4*>(xs);
#pragma unroll 4
    for (int j = 0; j < N_ATT / 4; ++j) {
        const float4 v = xs4[j];
        s0 += fabsf(xi - v.x);
        s1 += fabsf(xi - v.y);
        s2 += fabsf(xi - v.z);
        s3 += fabsf(xi - v.w);
    }
    float s = (s0 + s1) + (s2 + s3);

    // block reduce (wave=64)
#pragma unroll
    for (int off = 32; off > 0; off >>= 1) s += __shfl_down(s, off);
    __shared__ float wsum[THREADS / 64];
    const int lane = t & 63, wid = t >> 6;
    if (lane == 0) wsum[wid] = s;
    __syncthreads();
    if (t == 0) {
        float tot = 0.f;
#pragma unroll
        for (int w = 0; w < THREADS / 64; ++w) tot += wsum[w];
        ws[blockIdx.x] = tot;
    }
}

// Kernel 2: cross-entropy + combine. One block of 256 threads.
__global__ __launch_bounds__(THREADS)
void finalize(const float* __restrict__ logits, const int* __restrict__ labels,
              const float* __restrict__ ws, float* __restrict__ out) {
    const int t = threadIdx.x;

    float ce = 0.f;
    if (t < B_ROWS) {
        const float* lg = logits + t * C_CLS;
        float m = lg[0];
#pragma unroll
        for (int c = 1; c < C_CLS; ++c) m = fmaxf(m, lg[c]);
        float sum = 0.f;
#pragma unroll
        for (int c = 0; c < C_CLS; ++c) sum += expf(lg[c] - m);
        const float lse = m + logf(sum);
        ce = lse - lg[labels[t]];          // -log_softmax[label]
    }
    float g = ws[t];                       // exactly 256 partials

    float cs = ce, gs = g;
#pragma unroll
    for (int off = 32; off > 0; off >>= 1) {
        cs += __shfl_down(cs, off);
        gs += __shfl_down(gs, off);
    }
    __shared__ float sc[THREADS / 64], sg[THREADS / 64];
    const int lane = t & 63, wid = t >> 6;
    if (lane == 0) { sc[wid] = cs; sg[wid] = gs; }
    __syncthreads();
    if (t == 0) {
        float ce_tot = 0.f, g_tot = 0.f;
#pragma unroll
        for (int w = 0; w < THREADS / 64; ++w) { ce_tot += sc[w]; g_tot += sg[w]; }
        const float pred = ce_tot / (float)B_ROWS;
        const float info = g_tot / (2.0f * (float)N_ATT * (float)N_ATT + 1e-9f);
        out[0] = pred - BETA * info;
    }
}

extern "C" void kernel_launch(void* const* d_in, const int* in_sizes, int n_in,
                              void* d_out, int out_size, void* d_ws, size_t ws_size,
                              hipStream_t stream) {
    const float* att    = (const float*)d_in[0];   // [32, 2048] f32
    const float* logits = (const float*)d_in[1];   // [32, 10]   f32
    const int*   labels = (const int*)d_in[2];     // [32]       i32
    float* out = (float*)d_out;                    // scalar f32
    float* ws  = (float*)d_ws;                     // 256 floats of scratch

    gini_partial<<<B_ROWS * SPLITS, THREADS, 0, stream>>>(att, ws);
    finalize<<<1, THREADS, 0, stream>>>(logits, labels, ws, out);
}

// Round 2
// 16.273 us; speedup vs baseline: 1.3956x; 1.3956x over previous
//
#include <hip/hip_runtime.h>

#define N_ATT    2048
#define B_ROWS   32
#define THREADS  256
#define ISPLITS  8          // i-chunks of 256 per row
#define JSPLITS  4          // j-chunks of 512 per row
#define JCHUNK   (N_ATT / JSPLITS)   // 512
#define NBLOCKS  (B_ROWS * ISPLITS * JSPLITS)  // 1024
#define C_CLS    10
#define BETA     0.5f
#define EPS_ATT  1e-6f

// Kernel 1: per-(row, i-chunk, j-chunk) partial Gini sums.
// 1024 blocks -> 4 blocks/CU -> 4 waves/SIMD for latency hiding.
__global__ __launch_bounds__(THREADS)
void gini_partial(const float* __restrict__ att, float* __restrict__ ws) {
    __shared__ float xs[JCHUNK];
    const int b      = blockIdx.x;
    const int row    = b >> 5;            // / 32
    const int sub    = b & 31;
    const int isplit = sub >> 2;          // 0..7
    const int jsplit = sub & 3;           // 0..3
    const int t      = threadIdx.x;
    const float* a   = att + row * N_ATT;

    // stage this block's j-chunk (512 floats) into LDS as log(att+eps)
#pragma unroll
    for (int k = 0; k < JCHUNK / THREADS; ++k) {
        const int idx = t + k * THREADS;
        xs[idx] = logf(a[jsplit * JCHUNK + idx] + EPS_ATT);
    }
    const float xi = logf(a[isplit * THREADS + t] + EPS_ATT);
    __syncthreads();

    // sum_j |xi - xs[j]| over the 512-element chunk; float4 LDS broadcasts
    float s0 = 0.f, s1 = 0.f, s2 = 0.f, s3 = 0.f;
    const float4* xs4 = reinterpret_cast<const float4*>(xs);
#pragma unroll 8
    for (int j = 0; j < JCHUNK / 4; ++j) {
        const float4 v = xs4[j];
        s0 += fabsf(xi - v.x);
        s1 += fabsf(xi - v.y);
        s2 += fabsf(xi - v.z);
        s3 += fabsf(xi - v.w);
    }
    float s = (s0 + s1) + (s2 + s3);

    // block reduce (wave = 64)
#pragma unroll
    for (int off = 32; off > 0; off >>= 1) s += __shfl_down(s, off);
    __shared__ float wsum[THREADS / 64];
    const int lane = t & 63, wid = t >> 6;
    if (lane == 0) wsum[wid] = s;
    __syncthreads();
    if (t == 0) {
        float tot = 0.f;
#pragma unroll
        for (int w = 0; w < THREADS / 64; ++w) tot += wsum[w];
        ws[b] = tot;
    }
}

// Kernel 2: cross-entropy + combine. One block of 256 threads.
__global__ __launch_bounds__(THREADS)
void finalize(const float* __restrict__ logits, const int* __restrict__ labels,
              const float* __restrict__ ws, float* __restrict__ out) {
    const int t = threadIdx.x;

    float ce = 0.f;
    if (t < B_ROWS) {
        const float* lg = logits + t * C_CLS;
        float m = lg[0];
#pragma unroll
        for (int c = 1; c < C_CLS; ++c) m = fmaxf(m, lg[c]);
        float sum = 0.f;
#pragma unroll
        for (int c = 0; c < C_CLS; ++c) sum += expf(lg[c] - m);
        const float lse = m + logf(sum);
        ce = lse - lg[labels[t]];          // -log_softmax[label]
    }

    // 1024 partials, 4 per thread (fixed order -> deterministic)
    float g = ws[t] + ws[t + 256] + ws[t + 512] + ws[t + 768];

    float cs = ce, gs = g;
#pragma unroll
    for (int off = 32; off > 0; off >>= 1) {
        cs += __shfl_down(cs, off);
        gs += __shfl_down(gs, off);
    }
    __shared__ float sc[THREADS / 64], sg[THREADS / 64];
    const int lane = t & 63, wid = t >> 6;
    if (lane == 0) { sc[wid] = cs; sg[wid] = gs; }
    __syncthreads();
    if (t == 0) {
        float ce_tot = 0.f, g_tot = 0.f;
#pragma unroll
        for (int w = 0; w < THREADS / 64; ++w) { ce_tot += sc[w]; g_tot += sg[w]; }
        const float pred = ce_tot / (float)B_ROWS;
        const float info = g_tot / (2.0f * (float)N_ATT * (float)N_ATT + 1e-9f);
        out[0] = pred - BETA * info;
    }
}

extern "C" void kernel_launch(void* const* d_in, const int* in_sizes, int n_in,
                              void* d_out, int out_size, void* d_ws, size_t ws_size,
                              hipStream_t stream) {
    const float* att    = (const float*)d_in[0];   // [32, 2048] f32
    const float* logits = (const float*)d_in[1];   // [32, 10]   f32
    const int*   labels = (const int*)d_in[2];     // [32]       i32
    float* out = (float*)d_out;                    // scalar f32
    float* ws  = (float*)d_ws;                     // 1024 floats of scratch

    gini_partial<<<NBLOCKS, THREADS, 0, stream>>>(att, ws);
    finalize<<<1, THREADS, 0, stream>>>(logits, labels, ws, out);
}